// Round 9
// baseline (241.181 us; speedup 1.0000x reference)
//
#include <hip/hip_runtime.h>
#include <math.h>

#define N_NODES 50000
#define N_EDGES 800000

typedef __attribute__((ext_vector_type(8))) short bf16x8;
typedef __attribute__((ext_vector_type(4))) float f32x4;

// round-to-nearest-even float -> bf16 (bits in low 16)
__device__ __forceinline__ unsigned f2bfu(float f) {
  union { float f; unsigned u; } v; v.f = f;
  return (v.u + 0x7FFFu + ((v.u >> 16) & 1u)) >> 16;
}
__device__ __forceinline__ short f2bf(float f) { return (short)f2bfu(f); }

__device__ __forceinline__ float bflo(unsigned d) {
  union { unsigned u; float f; } v; v.u = d << 16; return v.f;
}
__device__ __forceinline__ float bfhi(unsigned d) {
  union { unsigned u; float f; } v; v.u = d & 0xFFFF0000u; return v.f;
}

// tanh-gelu (jax approximate=True). Overflow-safe (e=inf -> gelu=h).
__device__ __forceinline__ float gelu_f(float h) {
  const float m1 = h * h;
  const float t2u = h * fmaf(0.07135481f, m1, 1.5957691f);
  const float e = __expf(t2u);
  const float rc = __builtin_amdgcn_rcpf(1.f + e);
  return h - h * rc;
}

#define PIN(v) asm volatile("" : "+v"(v))

// ---------------------------------------------------------------------------
// Kernel 0: build bf16 MFMA weight fragments once (16 KB in ws).
//   wfrag[id], id = mat*512 + mb*64 + lane; lane=(gg<<4)|rr
//   frag[t] = W[(gg*8+t)*128 + 16*mb + rr]  (k=31 pad -> 0)
//   mat 0: W1e (rows 256..286 of W1), mat 1: W_proj
// ---------------------------------------------------------------------------
__global__ void wfrag_kernel(const float* __restrict__ W_proj,
                             const float* __restrict__ W1,
                             uint4* __restrict__ wfrag) {
  const int id = threadIdx.x;            // 0..1023
  const int mat = id >> 9;
  const int fid = id & 511;
  const int mb = fid >> 6, ln = fid & 63;
  const int rr = ln & 15, gg = ln >> 4;
  const float* W = mat ? W_proj : (W1 + (size_t)256 * 128);
  union { uint4 u; bf16x8 b; } f;
#pragma unroll
  for (int t = 0; t < 8; ++t) {
    const int kk = gg * 8 + t;
    f.b[t] = (kk < 31) ? f2bf(W[(size_t)kk * 128 + 16 * mb + rr]) : (short)0;
  }
  wfrag[id] = f.u;
}

// ---------------------------------------------------------------------------
// Kernel 1: AB (bf16, fragment-major layout) — unchanged from round 7.
//   ushort offset: n*256 + half*128 + g4*32 + mb8*4 + i
//   value = x[n] . Wab[:,c] + 0.5*b1[c mod 128]
// ---------------------------------------------------------------------------
__global__ __launch_bounds__(256) void node_kernel(
    const float* __restrict__ x, const float* __restrict__ W1,
    const float* __restrict__ b1, unsigned short* __restrict__ AB) {
  const int l = threadIdx.x & 63;
  const int wv = threadIdx.x >> 6;
  const int r = l & 15, g4 = l >> 4;

  const int wid = blockIdx.x * 4 + wv;
  const int s = wid & 3;                 // col strip: blocks mb = 4s+q

  bf16x8 wA[4][4];
#pragma unroll
  for (int q = 0; q < 4; ++q) {
    const int c = 16 * (4 * s + q) + r;
    const float* Wb = (c < 128) ? (W1 + c) : (W1 + 128 * 128 + (c - 128));
#pragma unroll
    for (int ks = 0; ks < 4; ++ks) {
#pragma unroll
      for (int t = 0; t < 8; ++t)
        wA[q][ks][t] = f2bf(Wb[(size_t)(ks * 32 + g4 * 8 + t) * 128]);
      PIN(wA[q][ks]);
    }
  }
  float4 bv[4];
#pragma unroll
  for (int q = 0; q < 4; ++q)
    bv[q] = *(const float4*)(b1 + ((16 * (4 * s + q) + g4 * 4) & 127));

  const int half = s >> 1;

  for (int t0 = wid >> 2; t0 < (N_NODES / 16); t0 += 1024) {
    const int n0 = t0 * 16;
    f32x4 acc[4] = {{0,0,0,0},{0,0,0,0},{0,0,0,0},{0,0,0,0}};
#pragma unroll
    for (int ks = 0; ks < 4; ++ks) {
      const float* xr = x + (size_t)(n0 + r) * 128 + ks * 32 + g4 * 8;
      const float4 x0 = *(const float4*)xr;
      const float4 x1 = *(const float4*)(xr + 4);
      bf16x8 xb;
      xb[0] = f2bf(x0.x); xb[1] = f2bf(x0.y); xb[2] = f2bf(x0.z); xb[3] = f2bf(x0.w);
      xb[4] = f2bf(x1.x); xb[5] = f2bf(x1.y); xb[6] = f2bf(x1.z); xb[7] = f2bf(x1.w);
#pragma unroll
      for (int q = 0; q < 4; ++q)
        acc[q] = __builtin_amdgcn_mfma_f32_16x16x32_bf16(wA[q][ks], xb, acc[q], 0, 0, 0);
    }
#pragma unroll
    for (int q = 0; q < 4; ++q) {
      const int mb8 = 4 * (s & 1) + q;
      const float o0 = acc[q][0] + 0.5f * bv[q].x;
      const float o1 = acc[q][1] + 0.5f * bv[q].y;
      const float o2 = acc[q][2] + 0.5f * bv[q].z;
      const float o3 = acc[q][3] + 0.5f * bv[q].w;
      uint2 pk;
      pk.x = f2bfu(o0) | (f2bfu(o1) << 16);
      pk.y = f2bfu(o2) | (f2bfu(o3) << 16);
      *(uint2*)(AB + (size_t)(n0 + r) * 256 + half * 128 + g4 * 32 + mb8 * 4) = pk;
    }
  }
}

// ---------------------------------------------------------------------------
// Kernel 2: fused edge kernel (round-7 orientation). One wave = 16 edges.
// Round-9 changes vs round 7:
//  - NO LDS: D fragments stored directly as f32x4 (per instruction 16 x 64 B
//    full lines; L2 write-combines -> 400 MB exact, per round-4 evidence)
//  - weight fragments loaded from precomputed ws table (16 coalesced 16 B
//    loads instead of 128 scattered loads + converts)
//  - next-tile edge-index prefetch (2 VGPR) to break the idx->gather chain
// ---------------------------------------------------------------------------
__global__ __launch_bounds__(256) void edge_kernel(
    const float* __restrict__ edge_attr, const int* __restrict__ edge_index,
    const unsigned short* __restrict__ AB, const uint4* __restrict__ wfrag,
    const float* __restrict__ b_proj, const float* __restrict__ W2,
    const float* __restrict__ b2, float* __restrict__ out) {
  const int l = threadIdx.x & 63;
  const int wv = threadIdx.x >> 6;
  const int r = l & 15, g4 = l >> 4;

  bf16x8 wH[8], wP[8];
#pragma unroll
  for (int mb = 0; mb < 8; ++mb) {
    union { uint4 u; bf16x8 b; } h, p;
    h.u = wfrag[mb * 64 + l];
    p.u = wfrag[512 + mb * 64 + l];
    wH[mb] = h.b; wP[mb] = p.b;
    PIN(wH[mb]); PIN(wP[mb]);
  }
  const float b2v = b2[0];

  const int nwaves = gridDim.x * 4;
  const int NT = N_EDGES / 16;

  int tile = blockIdx.x * 4 + wv;
  if (tile >= NT) return;
  int src = edge_index[tile * 16 + r];
  int dst = edge_index[N_EDGES + tile * 16 + r];

  for (; tile < NT; tile += nwaves) {
    const int e = tile * 16 + r;
    const int cs = src, cd = dst;

    // prefetch next tile's indices (breaks the idx->gather dependence)
    const int tn = tile + nwaves;
    if (tn < NT) {
      src = edge_index[tn * 16 + r];
      dst = edge_index[N_EDGES + tn * 16 + r];
    }

    // ea B-frag: b[t] = ea[e][g4*8+t], k=31 pad -> 0
    const float* ear = edge_attr + (size_t)e * 31 + g4 * 8;
    bf16x8 eb;
#pragma unroll
    for (int t = 0; t < 8; ++t) {
      const int kk = g4 * 8 + t;
      eb[t] = (kk < 31) ? f2bf(ear[t]) : (short)0;
    }

    // coalesced bf16 gathers: 64 B contiguous per lane per half
    const uint4* ap4 = (const uint4*)(AB + (size_t)cs * 256 + g4 * 32);
    const uint4* bp4 = (const uint4*)(AB + (size_t)cd * 256 + 128 + g4 * 32);
    uint4 ua[4], ub[4];
#pragma unroll
    for (int t = 0; t < 4; ++t) { ua[t] = ap4[t]; ub[t] = bp4[t]; }

    // unpack + combine into C: acch[mb][i]
    f32x4 acch[8];
#pragma unroll
    for (int t = 0; t < 4; ++t) {
      acch[2 * t][0]     = bflo(ua[t].x) + bflo(ub[t].x);
      acch[2 * t][1]     = bfhi(ua[t].x) + bfhi(ub[t].x);
      acch[2 * t][2]     = bflo(ua[t].y) + bflo(ub[t].y);
      acch[2 * t][3]     = bfhi(ua[t].y) + bfhi(ub[t].y);
      acch[2 * t + 1][0] = bflo(ua[t].z) + bflo(ub[t].z);
      acch[2 * t + 1][1] = bfhi(ua[t].z) + bfhi(ub[t].z);
      acch[2 * t + 1][2] = bflo(ua[t].w) + bflo(ub[t].w);
      acch[2 * t + 1][3] = bfhi(ua[t].w) + bfhi(ub[t].w);
    }
#pragma unroll
    for (int mb = 0; mb < 8; ++mb)
      acch[mb] = __builtin_amdgcn_mfma_f32_16x16x32_bf16(wH[mb], eb, acch[mb], 0, 0, 0);

    // gate logit: lane holds cols j = 16*mb + g4*4 + i of its edge
    float lg = 0.f;
#pragma unroll
    for (int mb = 0; mb < 8; ++mb) {
      const float4 w2v = *(const float4*)(W2 + 16 * mb + g4 * 4);
      lg = fmaf(gelu_f(acch[mb][0]), w2v.x, lg);
      lg = fmaf(gelu_f(acch[mb][1]), w2v.y, lg);
      lg = fmaf(gelu_f(acch[mb][2]), w2v.z, lg);
      lg = fmaf(gelu_f(acch[mb][3]), w2v.w, lg);
    }
    lg += __shfl_xor(lg, 16);
    lg += __shfl_xor(lg, 32);
    const float gate = __builtin_amdgcn_rcpf(1.f + __expf(-(lg + b2v)));

    // deferred base projection + direct full-line stores (plain, 16 B/lane)
    float* const orow = out + (size_t)e * 128 + 4 * g4;
#pragma unroll
    for (int mb = 0; mb < 8; ++mb) {
      f32x4 ac = __builtin_amdgcn_mfma_f32_16x16x32_bf16(
          wP[mb], eb, (f32x4){0.f, 0.f, 0.f, 0.f}, 0, 0, 0);
      const float4 bp = *(const float4*)(b_proj + 16 * mb + 4 * g4);
      f32x4 o;
      o[0] = (ac[0] + bp.x) * gate;
      o[1] = (ac[1] + bp.y) * gate;
      o[2] = (ac[2] + bp.z) * gate;
      o[3] = (ac[3] + bp.w) * gate;
      *(f32x4*)(orow + 16 * mb) = o;
    }
  }
}

extern "C" void kernel_launch(void* const* d_in, const int* in_sizes, int n_in,
                              void* d_out, int out_size, void* d_ws, size_t ws_size,
                              hipStream_t stream) {
  const float* x          = (const float*)d_in[0];
  const float* edge_attr  = (const float*)d_in[1];
  const int*   edge_index = (const int*)d_in[2];
  const float* W_proj     = (const float*)d_in[3];
  const float* b_proj     = (const float*)d_in[4];
  const float* W1         = (const float*)d_in[5];
  const float* b1         = (const float*)d_in[6];
  const float* W2         = (const float*)d_in[7];
  const float* b2         = (const float*)d_in[8];
  float* out = (float*)d_out;
  unsigned short* AB = (unsigned short*)d_ws;           // 25.6 MB
  uint4* wfrag = (uint4*)(AB + (size_t)N_NODES * 256);  // 16 KB, 16B-aligned

  hipLaunchKernelGGL(wfrag_kernel, dim3(1), dim3(1024), 0, stream,
                     W_proj, W1, wfrag);
  hipLaunchKernelGGL(node_kernel, dim3(1024), dim3(256), 0, stream,
                     x, W1, b1, AB);
  hipLaunchKernelGGL(edge_kernel, dim3(2048), dim3(256), 0, stream,
                     edge_attr, edge_index, AB, wfrag, b_proj, W2, b2,
                     out);
}